// Round 6
// baseline (91.330 us; speedup 1.0000x reference)
//
#include <hip/hip_runtime.h>
#include <stdint.h>

typedef unsigned int  uint32;
typedef unsigned long long u64;

#define L2E 1.44269504088896340736f

typedef float f32x4 __attribute__((ext_vector_type(4)));
typedef short bf16x8 __attribute__((ext_vector_type(8)));

__device__ __forceinline__ unsigned short f2bf(float f){
  uint32 u = __float_as_uint(f);
  u += 0x7fffu + ((u >> 16) & 1u);
  return (unsigned short)(u >> 16);
}

// k-permutation: k' -> j:  Q = k'>>8, p = (k'>>6)&3, l = k'&63, j = Q*256 + 4*l + p
// inverse:       j  -> k': Q = j>>8,  l = (j&255)>>2, p = j&3,  k' = Q*256 + p*64 + l
// gTp fragment layout: element (b, o, k') at
//   ((b*64 + (k'>>5))*8 + (o>>4))*512 + (((k'>>3)&3)*16 + (o&15))*8 + (k'&7)

// ---------------- K1: h = x @ W^T (bf16 split MFMA) + fused E1/E2p epilogue ----------------
__global__ __launch_bounds__(256) void k_h(const float* __restrict__ x,
                                           const float* __restrict__ W,
                                           const float* __restrict__ a1,
                                           const float* __restrict__ a2,
                                           const float* __restrict__ ab,
                                           float* __restrict__ h,
                                           float* __restrict__ E1,
                                           float* __restrict__ E2p){
  __shared__ unsigned short xs[2][64][72];    // [hi/lo][row][f] pad 72
  __shared__ unsigned short wsm[2][128][72];  // [hi/lo][o][f]
  const int tid = threadIdx.x;
  const int wv = tid >> 6, lane = tid & 63;
  const int r = lane & 15, kg = lane >> 4;
  const int row0 = blockIdx.x * 64;

  f32x4 acc[8];
  #pragma unroll
  for (int of = 0; of < 8; ++of) acc[of] = (f32x4){0.f,0.f,0.f,0.f};

  for (int kc = 0; kc < 4; ++kc){
    if (kc) __syncthreads();
    #pragma unroll
    for (int it = 0; it < 4; ++it){
      int idx = tid + it * 256;
      int row = idx >> 4, f = (idx & 15) * 4;
      float4 v = *(const float4*)(x + (size_t)(row0 + row) * 256 + kc * 64 + f);
      ushort4 hi, lo;
      { unsigned short hh = f2bf(v.x); float rr = v.x - __uint_as_float(((uint32)hh)<<16); hi.x = hh; lo.x = f2bf(rr); }
      { unsigned short hh = f2bf(v.y); float rr = v.y - __uint_as_float(((uint32)hh)<<16); hi.y = hh; lo.y = f2bf(rr); }
      { unsigned short hh = f2bf(v.z); float rr = v.z - __uint_as_float(((uint32)hh)<<16); hi.z = hh; lo.z = f2bf(rr); }
      { unsigned short hh = f2bf(v.w); float rr = v.w - __uint_as_float(((uint32)hh)<<16); hi.w = hh; lo.w = f2bf(rr); }
      *(ushort4*)&xs[0][row][f] = hi;
      *(ushort4*)&xs[1][row][f] = lo;
    }
    #pragma unroll
    for (int it = 0; it < 8; ++it){
      int idx = tid + it * 256;
      int o = idx >> 4, f = (idx & 15) * 4;
      float4 v = *(const float4*)(W + (size_t)o * 256 + kc * 64 + f);
      ushort4 hi, lo;
      { unsigned short hh = f2bf(v.x); float rr = v.x - __uint_as_float(((uint32)hh)<<16); hi.x = hh; lo.x = f2bf(rr); }
      { unsigned short hh = f2bf(v.y); float rr = v.y - __uint_as_float(((uint32)hh)<<16); hi.y = hh; lo.y = f2bf(rr); }
      { unsigned short hh = f2bf(v.z); float rr = v.z - __uint_as_float(((uint32)hh)<<16); hi.z = hh; lo.z = f2bf(rr); }
      { unsigned short hh = f2bf(v.w); float rr = v.w - __uint_as_float(((uint32)hh)<<16); hi.w = hh; lo.w = f2bf(rr); }
      *(ushort4*)&wsm[0][o][f] = hi;
      *(ushort4*)&wsm[1][o][f] = lo;
    }
    __syncthreads();
    #pragma unroll
    for (int kk = 0; kk < 2; ++kk){
      bf16x8 ah = *(const bf16x8*)&xs[0][wv*16 + r][kk*32 + kg*8];
      bf16x8 al = *(const bf16x8*)&xs[1][wv*16 + r][kk*32 + kg*8];
      #pragma unroll
      for (int of = 0; of < 8; ++of){
        bf16x8 bh = *(const bf16x8*)&wsm[0][of*16 + r][kk*32 + kg*8];
        bf16x8 bl = *(const bf16x8*)&wsm[1][of*16 + r][kk*32 + kg*8];
        acc[of] = __builtin_amdgcn_mfma_f32_16x16x32_bf16(ah, bh, acc[of], 0, 0, 0);
        acc[of] = __builtin_amdgcn_mfma_f32_16x16x32_bf16(ah, bl, acc[of], 0, 0, 0);
        acc[of] = __builtin_amdgcn_mfma_f32_16x16x32_bf16(al, bh, acc[of], 0, 0, 0);
      }
    }
  }
  #pragma unroll
  for (int of = 0; of < 8; ++of)
    #pragma unroll
    for (int q = 0; q < 4; ++q)
      h[(size_t)(row0 + wv*16 + kg*4 + q) * 128 + of*16 + r] = acc[of][q];

  float p1[4] = {0,0,0,0}, p2[4] = {0,0,0,0};
  #pragma unroll
  for (int of = 0; of < 8; ++of){
    float w1 = a1[of*16 + r], w2 = a2[of*16 + r];
    #pragma unroll
    for (int q = 0; q < 4; ++q){
      p1[q] = fmaf(acc[of][q], w1, p1[q]);
      p2[q] = fmaf(acc[of][q], w2, p2[q]);
    }
  }
  #pragma unroll
  for (int off = 8; off; off >>= 1)
    #pragma unroll
    for (int q = 0; q < 4; ++q){
      p1[q] += __shfl_xor(p1[q], off);
      p2[q] += __shfl_xor(p2[q], off);
    }
  if (r == 0){
    float abv = ab[0];
    #pragma unroll
    for (int q = 0; q < 4; ++q){
      int row = row0 + wv*16 + kg*4 + q;
      E1[row] = p1[q] * L2E;
      int bb = row >> 11, j = row & 2047;
      int kp = (j & ~255) + (j & 3) * 64 + ((j & 255) >> 2);
      E2p[bb * 2048 + kp] = (p2[q] + abv) * L2E;
    }
  }
}

// ---------------- K2: whole-row streaming denom partials + mask (k'-order words) ----------------
// 512 blocks; block bid: batch b=bid>>6, rowgroup g=bid&63 (32 rows). Wave = 8 consecutive
// rows, fully sequential 64KB stream. Lane accumulates ds[c][p] for j = c*256 + 4*lane + p.
#define KDM_ROWC(av, rrr)                                                       \
  {                                                                             \
    const float e1 = e1r[rrr];                                                  \
    u64 w = 0;                                                                  \
    _Pragma("unroll")                                                           \
    for (int c = 0; c < 8; ++c){                                                \
      float t0 = e1 + e2v[c][0]; t0 = fmaxf(t0, 0.2f * t0);                     \
      float t1 = e1 + e2v[c][1]; t1 = fmaxf(t1, 0.2f * t1);                     \
      float t2 = e1 + e2v[c][2]; t2 = fmaxf(t2, 0.2f * t2);                     \
      float t3 = e1 + e2v[c][3]; t3 = fmaxf(t3, 0.2f * t3);                     \
      ds[c][0] = fmaf((av)[c].x, __builtin_amdgcn_exp2f(t0), ds[c][0]);         \
      ds[c][1] = fmaf((av)[c].y, __builtin_amdgcn_exp2f(t1), ds[c][1]);         \
      ds[c][2] = fmaf((av)[c].z, __builtin_amdgcn_exp2f(t2), ds[c][2]);         \
      ds[c][3] = fmaf((av)[c].w, __builtin_amdgcn_exp2f(t3), ds[c][3]);         \
      u64 b0 = __ballot((av)[c].x != 0.f);                                      \
      u64 b1 = __ballot((av)[c].y != 0.f);                                      \
      u64 b2 = __ballot((av)[c].z != 0.f);                                      \
      u64 b3 = __ballot((av)[c].w != 0.f);                                      \
      w = (lane == c * 4 + 0) ? b0 : w;                                         \
      w = (lane == c * 4 + 1) ? b1 : w;                                         \
      w = (lane == c * 4 + 2) ? b2 : w;                                         \
      w = (lane == c * 4 + 3) ? b3 : w;                                         \
    }                                                                           \
    if (lane < 32) mp[(size_t)(rrr) * 32 + lane] = w;                           \
  }

__global__ __launch_bounds__(256) void k_dm(const float* __restrict__ adj,
                                            const float* __restrict__ E1,
                                            const float* __restrict__ E2p,
                                            float* __restrict__ denomP,
                                            u64* __restrict__ mask){
  __shared__ float red[4][2048];
  const int bid = blockIdx.x;
  const int b = bid >> 6, g = bid & 63;
  const int wv = threadIdx.x >> 6, lane = threadIdx.x & 63;
  const int row0 = b * 2048 + g * 32 + wv * 8;   // global flattened row

  float e2v[8][4];
  #pragma unroll
  for (int c = 0; c < 8; ++c)
    #pragma unroll
    for (int p = 0; p < 4; ++p)
      e2v[c][p] = E2p[b * 2048 + c * 256 + p * 64 + lane];

  float ds[8][4];
  #pragma unroll
  for (int c = 0; c < 8; ++c)
    #pragma unroll
    for (int p = 0; p < 4; ++p) ds[c][p] = 0.f;

  const float4* ap = (const float4*)(adj + (size_t)row0 * 2048) + lane;
  u64* mp = mask + (size_t)row0 * 32;

  // all 8 row-scalars upfront (uniform loads)
  float4 e1a = *(const float4*)(E1 + row0);
  float4 e1b = *(const float4*)(E1 + row0 + 4);
  float e1r[8] = {e1a.x, e1a.y, e1a.z, e1a.w, e1b.x, e1b.y, e1b.z, e1b.w};

  float4 avA[8], avB[8];
  #pragma unroll
  for (int c = 0; c < 8; ++c) avA[c] = ap[c * 64];

  #pragma unroll
  for (int rp = 0; rp < 4; ++rp){
    const int r0 = rp * 2;
    #pragma unroll
    for (int c = 0; c < 8; ++c) avB[c] = ap[(size_t)(r0 + 1) * 512 + c * 64];
    KDM_ROWC(avA, r0)
    if (rp < 3){
      #pragma unroll
      for (int c = 0; c < 8; ++c) avA[c] = ap[(size_t)(r0 + 2) * 512 + c * 64];
    }
    KDM_ROWC(avB, r0 + 1)
  }

  #pragma unroll
  for (int c = 0; c < 8; ++c)
    *(float4*)&red[wv][c * 256 + lane * 4] = (float4){ds[c][0], ds[c][1], ds[c][2], ds[c][3]};
  __syncthreads();
  #pragma unroll
  for (int it = 0; it < 8; ++it){
    int j = it * 256 + threadIdx.x;
    denomP[(size_t)g * 16384 + b * 2048 + j] = red[0][j] + red[1][j] + red[2][j] + red[3][j];
  }
}

// ---------------- K2b: rinv = 1 / sum_g denomP ----------------
__global__ __launch_bounds__(256) void k_red(const float* __restrict__ denomP,
                                             float* __restrict__ rinv){
  const int n = blockIdx.x * 256 + threadIdx.x;
  float s = 0.f;
  #pragma unroll
  for (int gg = 0; gg < 64; ++gg)
    s += denomP[(size_t)gg * 16384 + n];
  rinv[n] = 1.0f / s;
}

// ---------------- K3: gTp[frag-order] = bf16( h[b][j(k')][o] * rinv[j(k')] ) ----------------
__global__ __launch_bounds__(256) void k_gt(const float* __restrict__ h,
                                            const float* __restrict__ rinv,
                                            unsigned short* __restrict__ gTp){
  __shared__ float hl[8464];   // index: j*33 + (j>>4) + oo,  oo<32 (local node order)
  __shared__ float rrec[256];
  const int b = blockIdx.z, Q = blockIdx.x, ot = blockIdx.y;
  const int o0 = ot * 32;
  const int tid = threadIdx.x;

  rrec[tid] = rinv[b * 2048 + Q * 256 + tid];
  __syncthreads();

  #pragma unroll
  for (int it = 0; it < 8; ++it){
    int idx = tid + it * 256;
    int j = idx >> 3, f = idx & 7;
    float4 v = *(const float4*)(h + (size_t)(b * 2048 + Q * 256 + j) * 128 + o0 + f * 4);
    float rc = rrec[j];
    int base = j * 33 + (j >> 4) + f * 4;
    hl[base + 0] = v.x * rc;
    hl[base + 1] = v.y * rc;
    hl[base + 2] = v.z * rc;
    hl[base + 3] = v.w * rc;
  }
  __syncthreads();

  const int u  = tid & 127;
  const int fh = tid >> 7;
  const int lane = u >> 1;
  const int e0 = (u & 1) * 4;
  const int orow_r = lane & 15;
  const int kgrp = lane >> 4;
  #pragma unroll
  for (int it = 0; it < 8; ++it){
    int f  = it * 2 + fh;
    int kb = f >> 1, sl = f & 1;
    int orow = sl * 16 + orow_r;
    int klb = kb * 32 + kgrp * 8 + e0;
    ushort4 uu;
    { int kl = klb + 0; int jl = 4 * (kl & 63) + (kl >> 6); uu.x = f2bf(hl[jl * 33 + (jl >> 4) + orow]); }
    { int kl = klb + 1; int jl = 4 * (kl & 63) + (kl >> 6); uu.y = f2bf(hl[jl * 33 + (jl >> 4) + orow]); }
    { int kl = klb + 2; int jl = 4 * (kl & 63) + (kl >> 6); uu.z = f2bf(hl[jl * 33 + (jl >> 4) + orow]); }
    { int kl = klb + 3; int jl = 4 * (kl & 63) + (kl >> 6); uu.w = f2bf(hl[jl * 33 + (jl >> 4) + orow]); }
    size_t dst = ((size_t)((b * 64 + Q * 8 + kb) * 8 + (ot * 2 + sl))) * 512 + lane * 8 + e0;
    *(ushort4*)(gTp + dst) = uu;
  }
}

// ---------------- K4: out = ELU( A @ g ), A synthesized, B coalesced frag loads ----------------
__global__ __launch_bounds__(256) void k_main(const float* __restrict__ E1,
                                              const float* __restrict__ E2p,
                                              const uint32* __restrict__ mask32,
                                              const unsigned short* __restrict__ gTp,
                                              float* __restrict__ out){
  __shared__ float cmb[4][32][129];
  const int b  = blockIdx.y;
  const int ib = blockIdx.x;
  const int wv = threadIdx.x >> 6, lane = threadIdx.x & 63;
  const int r  = lane & 15, kg = lane >> 4;
  const int gi0 = b * 2048 + ib * 32 + r;
  const float e1_0 = E1[gi0];
  const float e1_1 = E1[gi0 + 16];
  const uint32* m0 = mask32 + (size_t)gi0 * 64;
  const uint32* m1 = mask32 + (size_t)(gi0 + 16) * 64;

  f32x4 acc[2][8];
  #pragma unroll
  for (int si = 0; si < 2; ++si)
    #pragma unroll
    for (int so = 0; so < 8; ++so)
      acc[si][so] = (f32x4){0.f, 0.f, 0.f, 0.f};

  const int k0 = wv * 512, k1 = k0 + 512;
  for (int kk = k0; kk < k1; kk += 32){
    const int j0 = kk + kg * 8;
    const float4 eA = *(const float4*)(E2p + b * 2048 + j0);
    const float4 eB = *(const float4*)(E2p + b * 2048 + j0 + 4);
    const uint32 bits0 = (m0[kk >> 5] >> (kg * 8)) & 0xffu;
    const uint32 bits1 = (m1[kk >> 5] >> (kg * 8)) & 0xffu;
    float e2v[8] = {eA.x, eA.y, eA.z, eA.w, eB.x, eB.y, eB.z, eB.w};

    union { uint32 u[4]; bf16x8 v; } af0, af1;
    #pragma unroll
    for (int p = 0; p < 4; ++p){
      {
        float t0 = e1_0 + e2v[2*p];     t0 = fmaxf(t0, 0.2f * t0);
        float t1 = e1_0 + e2v[2*p+1];   t1 = fmaxf(t1, 0.2f * t1);
        float x0 = ((bits0 >> (2*p))   & 1u) ? __builtin_amdgcn_exp2f(t0) : 0.f;
        float x1 = ((bits0 >> (2*p+1)) & 1u) ? __builtin_amdgcn_exp2f(t1) : 0.f;
        uint32 u0 = __float_as_uint(x0); u0 = (u0 + 0x7fffu + ((u0 >> 16) & 1u)) >> 16;
        uint32 u1 = __float_as_uint(x1); u1 = (u1 + 0x7fffu + ((u1 >> 16) & 1u)) & 0xffff0000u;
        af0.u[p] = u0 | u1;
      }
      {
        float t0 = e1_1 + e2v[2*p];     t0 = fmaxf(t0, 0.2f * t0);
        float t1 = e1_1 + e2v[2*p+1];   t1 = fmaxf(t1, 0.2f * t1);
        float x0 = ((bits1 >> (2*p))   & 1u) ? __builtin_amdgcn_exp2f(t0) : 0.f;
        float x1 = ((bits1 >> (2*p+1)) & 1u) ? __builtin_amdgcn_exp2f(t1) : 0.f;
        uint32 u0 = __float_as_uint(x0); u0 = (u0 + 0x7fffu + ((u0 >> 16) & 1u)) >> 16;
        uint32 u1 = __float_as_uint(x1); u1 = (u1 + 0x7fffu + ((u1 >> 16) & 1u)) & 0xffff0000u;
        af1.u[p] = u0 | u1;
      }
    }
    const unsigned short* gk = gTp + ((size_t)(b * 64 + (kk >> 5)) * 8) * 512 + lane * 8;
    #pragma unroll
    for (int so = 0; so < 8; ++so){
      bf16x8 bfr = *(const bf16x8*)(gk + so * 512);
      acc[0][so] = __builtin_amdgcn_mfma_f32_16x16x32_bf16(af0.v, bfr, acc[0][so], 0, 0, 0);
      acc[1][so] = __builtin_amdgcn_mfma_f32_16x16x32_bf16(af1.v, bfr, acc[1][so], 0, 0, 0);
    }
  }

  #pragma unroll
  for (int si = 0; si < 2; ++si)
    #pragma unroll
    for (int so = 0; so < 8; ++so)
      #pragma unroll
      for (int q = 0; q < 4; ++q){
        int il = si * 16 + kg * 4 + q;
        int o  = so * 16 + r;
        cmb[wv][il][o] = acc[si][so][q];
      }
  __syncthreads();
  for (int e = threadIdx.x; e < 4096; e += 256){
    int i = e >> 7, o = e & 127;
    float v = cmb[0][i][o] + cmb[1][i][o] + cmb[2][i][o] + cmb[3][i][o];
    float res = v > 0.f ? v : (__builtin_amdgcn_exp2f(v * L2E) - 1.0f);
    out[(size_t)(b * 2048 + ib * 32 + i) * 128 + o] = res;
  }
}

// ---------------- launch ----------------
extern "C" void kernel_launch(void* const* d_in, const int* in_sizes, int n_in,
                              void* d_out, int out_size, void* d_ws, size_t ws_size,
                              hipStream_t stream){
  const float* x   = (const float*)d_in[0];
  const float* adj = (const float*)d_in[1];
  const float* W   = (const float*)d_in[2];
  const float* a1  = (const float*)d_in[3];
  const float* a2  = (const float*)d_in[4];
  const float* ab  = (const float*)d_in[5];
  float* out = (float*)d_out;

  // ws layout (bytes):
  //   h      f32 [16384*128]        @ 0          (8,388,608)
  //   E1     f32 [16384]            @ 8388608    (65,536)
  //   E2p    f32 [16384]            @ 8454144    (65,536)
  //   rinv   f32 [16384]            @ 8519680    (65,536)
  //   dpgt   denomP[64][16384] f32 OVERLAID with gTp bf16[8*64*8*512]
  //                                 @ 8585216    (4,194,304)
  //          (denomP dead after k_red; gTp written by k_gt afterwards)
  //   mask   u64 [8*2048*32]        @ 12779520   (4,194,304)
  const size_t WS_NEEDED = 16973824;
  if (ws_size < WS_NEEDED) return;

  char* ws = (char*)d_ws;
  float* h      = (float*)(ws);
  float* E1     = (float*)(ws + 8388608);
  float* E2p    = (float*)(ws + 8454144);
  float* rinv   = (float*)(ws + 8519680);
  float* denomP = (float*)(ws + 8585216);
  unsigned short* gTp = (unsigned short*)(ws + 8585216);
  u64*   mask   = (u64*)  (ws + 12779520);

  k_h  <<<256, 256, 0, stream>>>(x, W, a1, a2, ab, h, E1, E2p);
  k_dm <<<512, 256, 0, stream>>>(adj, E1, E2p, denomP, mask);
  k_red<<<64, 256, 0, stream>>>(denomP, rinv);
  k_gt <<<dim3(8, 4, 8), 256, 0, stream>>>(h, rinv, gTp);
  k_main<<<dim3(64, 8), 256, 0, stream>>>(E1, E2p, (const uint32*)mask, gTp, out);
}

// Round 8
// 77.918 us; speedup vs baseline: 1.1721x; 1.1721x over previous
//
#include <hip/hip_runtime.h>
#include <stdint.h>

typedef unsigned int  uint32;
typedef unsigned long long u64;

#define L2E 1.44269504088896340736f

typedef float f32x4 __attribute__((ext_vector_type(4)));
typedef short bf16x8 __attribute__((ext_vector_type(8)));

__device__ __forceinline__ unsigned short f2bf(float f){
  uint32 u = __float_as_uint(f);
  u += 0x7fffu + ((u >> 16) & 1u);
  return (unsigned short)(u >> 16);
}

// k-permutation: k' -> j:  Q = k'>>8, p = (k'>>6)&3, l = k'&63, j = Q*256 + 4*l + p
// inverse:       j  -> k': Q = j>>8,  l = (j&255)>>2, p = j&3,  k' = Q*256 + p*64 + l
// gTp fragment layout: element (b, o, k') at
//   ((b*64 + (k'>>5))*8 + (o>>4))*512 + (((k'>>3)&3)*16 + (o&15))*8 + (k'&7)

// ---------------- K1: h = x @ W^T (bf16 split MFMA) + fused E1/E2p epilogue ----------------
__global__ __launch_bounds__(256) void k_h(const float* __restrict__ x,
                                           const float* __restrict__ W,
                                           const float* __restrict__ a1,
                                           const float* __restrict__ a2,
                                           const float* __restrict__ ab,
                                           float* __restrict__ h,
                                           float* __restrict__ E1,
                                           float* __restrict__ E2p){
  __shared__ unsigned short xs[2][64][72];    // [hi/lo][row][f] pad 72
  __shared__ unsigned short wsm[2][128][72];  // [hi/lo][o][f]
  const int tid = threadIdx.x;
  const int wv = tid >> 6, lane = tid & 63;
  const int r = lane & 15, kg = lane >> 4;
  const int row0 = blockIdx.x * 64;

  f32x4 acc[8];
  #pragma unroll
  for (int of = 0; of < 8; ++of) acc[of] = (f32x4){0.f,0.f,0.f,0.f};

  for (int kc = 0; kc < 4; ++kc){
    if (kc) __syncthreads();
    #pragma unroll
    for (int it = 0; it < 4; ++it){
      int idx = tid + it * 256;
      int row = idx >> 4, f = (idx & 15) * 4;
      float4 v = *(const float4*)(x + (size_t)(row0 + row) * 256 + kc * 64 + f);
      ushort4 hi, lo;
      { unsigned short hh = f2bf(v.x); float rr = v.x - __uint_as_float(((uint32)hh)<<16); hi.x = hh; lo.x = f2bf(rr); }
      { unsigned short hh = f2bf(v.y); float rr = v.y - __uint_as_float(((uint32)hh)<<16); hi.y = hh; lo.y = f2bf(rr); }
      { unsigned short hh = f2bf(v.z); float rr = v.z - __uint_as_float(((uint32)hh)<<16); hi.z = hh; lo.z = f2bf(rr); }
      { unsigned short hh = f2bf(v.w); float rr = v.w - __uint_as_float(((uint32)hh)<<16); hi.w = hh; lo.w = f2bf(rr); }
      *(ushort4*)&xs[0][row][f] = hi;
      *(ushort4*)&xs[1][row][f] = lo;
    }
    #pragma unroll
    for (int it = 0; it < 8; ++it){
      int idx = tid + it * 256;
      int o = idx >> 4, f = (idx & 15) * 4;
      float4 v = *(const float4*)(W + (size_t)o * 256 + kc * 64 + f);
      ushort4 hi, lo;
      { unsigned short hh = f2bf(v.x); float rr = v.x - __uint_as_float(((uint32)hh)<<16); hi.x = hh; lo.x = f2bf(rr); }
      { unsigned short hh = f2bf(v.y); float rr = v.y - __uint_as_float(((uint32)hh)<<16); hi.y = hh; lo.y = f2bf(rr); }
      { unsigned short hh = f2bf(v.z); float rr = v.z - __uint_as_float(((uint32)hh)<<16); hi.z = hh; lo.z = f2bf(rr); }
      { unsigned short hh = f2bf(v.w); float rr = v.w - __uint_as_float(((uint32)hh)<<16); hi.w = hh; lo.w = f2bf(rr); }
      *(ushort4*)&wsm[0][o][f] = hi;
      *(ushort4*)&wsm[1][o][f] = lo;
    }
    __syncthreads();
    #pragma unroll
    for (int kk = 0; kk < 2; ++kk){
      bf16x8 ah = *(const bf16x8*)&xs[0][wv*16 + r][kk*32 + kg*8];
      bf16x8 al = *(const bf16x8*)&xs[1][wv*16 + r][kk*32 + kg*8];
      #pragma unroll
      for (int of = 0; of < 8; ++of){
        bf16x8 bh = *(const bf16x8*)&wsm[0][of*16 + r][kk*32 + kg*8];
        bf16x8 bl = *(const bf16x8*)&wsm[1][of*16 + r][kk*32 + kg*8];
        acc[of] = __builtin_amdgcn_mfma_f32_16x16x32_bf16(ah, bh, acc[of], 0, 0, 0);
        acc[of] = __builtin_amdgcn_mfma_f32_16x16x32_bf16(ah, bl, acc[of], 0, 0, 0);
        acc[of] = __builtin_amdgcn_mfma_f32_16x16x32_bf16(al, bh, acc[of], 0, 0, 0);
      }
    }
  }
  #pragma unroll
  for (int of = 0; of < 8; ++of)
    #pragma unroll
    for (int q = 0; q < 4; ++q)
      h[(size_t)(row0 + wv*16 + kg*4 + q) * 128 + of*16 + r] = acc[of][q];

  float p1[4] = {0,0,0,0}, p2[4] = {0,0,0,0};
  #pragma unroll
  for (int of = 0; of < 8; ++of){
    float w1 = a1[of*16 + r], w2 = a2[of*16 + r];
    #pragma unroll
    for (int q = 0; q < 4; ++q){
      p1[q] = fmaf(acc[of][q], w1, p1[q]);
      p2[q] = fmaf(acc[of][q], w2, p2[q]);
    }
  }
  #pragma unroll
  for (int off = 8; off; off >>= 1)
    #pragma unroll
    for (int q = 0; q < 4; ++q){
      p1[q] += __shfl_xor(p1[q], off);
      p2[q] += __shfl_xor(p2[q], off);
    }
  if (r == 0){
    float abv = ab[0];
    #pragma unroll
    for (int q = 0; q < 4; ++q){
      int row = row0 + wv*16 + kg*4 + q;
      E1[row] = p1[q] * L2E;
      int bb = row >> 11, j = row & 2047;
      int kp = (j & ~255) + (j & 3) * 64 + ((j & 255) >> 2);
      E2p[bb * 2048 + kp] = (p2[q] + abv) * L2E;
    }
  }
}

// ---------------- K2: denom partials + mask, simple body (compiler-pipelined) ----------------
// grid (Q=8, ic=32, b=8) = 2048 blocks (8/CU), 4 waves/block; wave: 16 rows x 256 j.
__global__ __launch_bounds__(256) void k_dm(const float* __restrict__ adj,
                                            const float* __restrict__ E1,
                                            const float* __restrict__ E2p,
                                            float* __restrict__ denomP,
                                            u64* __restrict__ mask){
  __shared__ float red[4][256];
  const int b = blockIdx.z, Q = blockIdx.x, ic = blockIdx.y;
  const int wv = threadIdx.x >> 6, lane = threadIdx.x & 63;
  const int Jbase = Q * 256;
  const int row0 = ic * 64 + wv * 16;         // row within batch
  const int grow0 = b * 2048 + row0;          // global flattened row

  const f32x4* ap = (const f32x4*)(adj + (size_t)grow0 * 2048 + Jbase) + lane;
  u64* mp = mask + (size_t)grow0 * 32 + Q * 4;

  float e2v[4];
  #pragma unroll
  for (int p = 0; p < 4; ++p)
    e2v[p] = E2p[b * 2048 + Q * 256 + p * 64 + lane];

  float e1r[16];
  #pragma unroll
  for (int q = 0; q < 4; ++q){
    float4 t = *(const float4*)(E1 + grow0 + q * 4);
    e1r[q*4+0] = t.x; e1r[q*4+1] = t.y; e1r[q*4+2] = t.z; e1r[q*4+3] = t.w;
  }

  float ds0 = 0.f, ds1 = 0.f, ds2 = 0.f, ds3 = 0.f;

  #pragma unroll
  for (int rr = 0; rr < 16; ++rr){
    f32x4 av = __builtin_nontemporal_load(ap + (size_t)rr * 512);
    const float e1 = e1r[rr];
    float t0 = e1 + e2v[0]; t0 = fmaxf(t0, 0.2f * t0);
    float t1 = e1 + e2v[1]; t1 = fmaxf(t1, 0.2f * t1);
    float t2 = e1 + e2v[2]; t2 = fmaxf(t2, 0.2f * t2);
    float t3 = e1 + e2v[3]; t3 = fmaxf(t3, 0.2f * t3);
    ds0 = fmaf(av[0], __builtin_amdgcn_exp2f(t0), ds0);
    ds1 = fmaf(av[1], __builtin_amdgcn_exp2f(t1), ds1);
    ds2 = fmaf(av[2], __builtin_amdgcn_exp2f(t2), ds2);
    ds3 = fmaf(av[3], __builtin_amdgcn_exp2f(t3), ds3);
    u64 b0 = __ballot(av[0] != 0.f);
    u64 b1 = __ballot(av[1] != 0.f);
    u64 b2 = __ballot(av[2] != 0.f);
    u64 b3 = __ballot(av[3] != 0.f);
    if (lane == 0){
      ulonglong2* dst = (ulonglong2*)(mp + (size_t)rr * 32);
      dst[0] = (ulonglong2){b0, b1};
      dst[1] = (ulonglong2){b2, b3};
    }
  }

  *(float4*)&red[wv][lane * 4] = (float4){ds0, ds1, ds2, ds3};
  __syncthreads();
  const int t = threadIdx.x;
  denomP[(size_t)ic * 16384 + b * 2048 + Jbase + t] = red[0][t] + red[1][t] + red[2][t] + red[3][t];
}

// ---------------- K3: gTp[frag-order] = bf16( h[b][j(k')][o] / denom[j(k')] ) ----------------
// grid (Q=8, ot=4, b=8)
__global__ __launch_bounds__(256) void k_gt(const float* __restrict__ h,
                                            const float* __restrict__ denomP,
                                            unsigned short* __restrict__ gTp){
  __shared__ float hl[8464];   // index: j*33 + (j>>4) + oo,  oo<32 (local node order)
  __shared__ float rrec[256];
  const int b = blockIdx.z, Q = blockIdx.x, ot = blockIdx.y;
  const int o0 = ot * 32;
  const int tid = threadIdx.x;

  {
    float d = 0.f;
    #pragma unroll
    for (int icc = 0; icc < 32; ++icc)
      d += denomP[(size_t)icc * 16384 + b * 2048 + Q * 256 + tid];
    rrec[tid] = 1.0f / d;
  }
  __syncthreads();

  #pragma unroll
  for (int it = 0; it < 8; ++it){
    int idx = tid + it * 256;
    int j = idx >> 3, f = idx & 7;
    float4 v = *(const float4*)(h + (size_t)(b * 2048 + Q * 256 + j) * 128 + o0 + f * 4);
    float rc = rrec[j];
    int base = j * 33 + (j >> 4) + f * 4;
    hl[base + 0] = v.x * rc;
    hl[base + 1] = v.y * rc;
    hl[base + 2] = v.z * rc;
    hl[base + 3] = v.w * rc;
  }
  __syncthreads();

  const int u  = tid & 127;
  const int fh = tid >> 7;
  const int lane = u >> 1;
  const int e0 = (u & 1) * 4;
  const int orow_r = lane & 15;
  const int kgrp = lane >> 4;
  #pragma unroll
  for (int it = 0; it < 8; ++it){
    int f  = it * 2 + fh;
    int kb = f >> 1, sl = f & 1;
    int orow = sl * 16 + orow_r;
    int klb = kb * 32 + kgrp * 8 + e0;
    ushort4 uu;
    { int kl = klb + 0; int jl = 4 * (kl & 63) + (kl >> 6); uu.x = f2bf(hl[jl * 33 + (jl >> 4) + orow]); }
    { int kl = klb + 1; int jl = 4 * (kl & 63) + (kl >> 6); uu.y = f2bf(hl[jl * 33 + (jl >> 4) + orow]); }
    { int kl = klb + 2; int jl = 4 * (kl & 63) + (kl >> 6); uu.z = f2bf(hl[jl * 33 + (jl >> 4) + orow]); }
    { int kl = klb + 3; int jl = 4 * (kl & 63) + (kl >> 6); uu.w = f2bf(hl[jl * 33 + (jl >> 4) + orow]); }
    size_t dst = ((size_t)((b * 64 + Q * 8 + kb) * 8 + (ot * 2 + sl))) * 512 + lane * 8 + e0;
    *(ushort4*)(gTp + dst) = uu;
  }
}

// ---------------- K4: out = ELU( A @ g ), A synthesized, B coalesced frag loads ----------------
__global__ __launch_bounds__(256) void k_main(const float* __restrict__ E1,
                                              const float* __restrict__ E2p,
                                              const uint32* __restrict__ mask32,
                                              const unsigned short* __restrict__ gTp,
                                              float* __restrict__ out){
  __shared__ float cmb[4][32][129];
  const int b  = blockIdx.y;
  const int ib = blockIdx.x;
  const int wv = threadIdx.x >> 6, lane = threadIdx.x & 63;
  const int r  = lane & 15, kg = lane >> 4;
  const int gi0 = b * 2048 + ib * 32 + r;
  const float e1_0 = E1[gi0];
  const float e1_1 = E1[gi0 + 16];
  const uint32* m0 = mask32 + (size_t)gi0 * 64;
  const uint32* m1 = mask32 + (size_t)(gi0 + 16) * 64;

  f32x4 acc[2][8];
  #pragma unroll
  for (int si = 0; si < 2; ++si)
    #pragma unroll
    for (int so = 0; so < 8; ++so)
      acc[si][so] = (f32x4){0.f, 0.f, 0.f, 0.f};

  const int k0 = wv * 512, k1 = k0 + 512;
  for (int kk = k0; kk < k1; kk += 32){
    const int j0 = kk + kg * 8;
    const float4 eA = *(const float4*)(E2p + b * 2048 + j0);
    const float4 eB = *(const float4*)(E2p + b * 2048 + j0 + 4);
    const uint32 bits0 = (m0[kk >> 5] >> (kg * 8)) & 0xffu;
    const uint32 bits1 = (m1[kk >> 5] >> (kg * 8)) & 0xffu;
    float e2v[8] = {eA.x, eA.y, eA.z, eA.w, eB.x, eB.y, eB.z, eB.w};

    union { uint32 u[4]; bf16x8 v; } af0, af1;
    #pragma unroll
    for (int p = 0; p < 4; ++p){
      {
        float t0 = e1_0 + e2v[2*p];     t0 = fmaxf(t0, 0.2f * t0);
        float t1 = e1_0 + e2v[2*p+1];   t1 = fmaxf(t1, 0.2f * t1);
        float x0 = ((bits0 >> (2*p))   & 1u) ? __builtin_amdgcn_exp2f(t0) : 0.f;
        float x1 = ((bits0 >> (2*p+1)) & 1u) ? __builtin_amdgcn_exp2f(t1) : 0.f;
        uint32 u0 = __float_as_uint(x0); u0 = (u0 + 0x7fffu + ((u0 >> 16) & 1u)) >> 16;
        uint32 u1 = __float_as_uint(x1); u1 = (u1 + 0x7fffu + ((u1 >> 16) & 1u)) & 0xffff0000u;
        af0.u[p] = u0 | u1;
      }
      {
        float t0 = e1_1 + e2v[2*p];     t0 = fmaxf(t0, 0.2f * t0);
        float t1 = e1_1 + e2v[2*p+1];   t1 = fmaxf(t1, 0.2f * t1);
        float x0 = ((bits1 >> (2*p))   & 1u) ? __builtin_amdgcn_exp2f(t0) : 0.f;
        float x1 = ((bits1 >> (2*p+1)) & 1u) ? __builtin_amdgcn_exp2f(t1) : 0.f;
        uint32 u0 = __float_as_uint(x0); u0 = (u0 + 0x7fffu + ((u0 >> 16) & 1u)) >> 16;
        uint32 u1 = __float_as_uint(x1); u1 = (u1 + 0x7fffu + ((u1 >> 16) & 1u)) & 0xffff0000u;
        af1.u[p] = u0 | u1;
      }
    }
    const unsigned short* gk = gTp + ((size_t)(b * 64 + (kk >> 5)) * 8) * 512 + lane * 8;
    #pragma unroll
    for (int so = 0; so < 8; ++so){
      bf16x8 bfr = *(const bf16x8*)(gk + so * 512);
      acc[0][so] = __builtin_amdgcn_mfma_f32_16x16x32_bf16(af0.v, bfr, acc[0][so], 0, 0, 0);
      acc[1][so] = __builtin_amdgcn_mfma_f32_16x16x32_bf16(af1.v, bfr, acc[1][so], 0, 0, 0);
    }
  }

  #pragma unroll
  for (int si = 0; si < 2; ++si)
    #pragma unroll
    for (int so = 0; so < 8; ++so)
      #pragma unroll
      for (int q = 0; q < 4; ++q){
        int il = si * 16 + kg * 4 + q;
        int o  = so * 16 + r;
        cmb[wv][il][o] = acc[si][so][q];
      }
  __syncthreads();
  for (int e = threadIdx.x; e < 4096; e += 256){
    int i = e >> 7, o = e & 127;
    float v = cmb[0][i][o] + cmb[1][i][o] + cmb[2][i][o] + cmb[3][i][o];
    float res = v > 0.f ? v : (__builtin_amdgcn_exp2f(v * L2E) - 1.0f);
    out[(size_t)(b * 2048 + ib * 32 + i) * 128 + o] = res;
  }
}

// ---------------- launch ----------------
extern "C" void kernel_launch(void* const* d_in, const int* in_sizes, int n_in,
                              void* d_out, int out_size, void* d_ws, size_t ws_size,
                              hipStream_t stream){
  const float* x   = (const float*)d_in[0];
  const float* adj = (const float*)d_in[1];
  const float* W   = (const float*)d_in[2];
  const float* a1  = (const float*)d_in[3];
  const float* a2  = (const float*)d_in[4];
  const float* ab  = (const float*)d_in[5];
  float* out = (float*)d_out;

  // ws layout (bytes):
  //   h      f32 [16384*128]      @ 0          (8,388,608)
  //   E1     f32 [16384]          @ 8388608    (65,536)
  //   E2p    f32 [16384]          @ 8454144    (65,536)
  //   denomP f32 [32][16384]      @ 8519680    (2,097,152)
  //   mask   u64 [8*2048*32]      @ 10616832   (4,194,304)
  //   gTp    bf16[8*64*8*512]     @ 14811136   (4,194,304)
  const size_t WS_NEEDED = 19005440;
  if (ws_size < WS_NEEDED) return;

  char* ws = (char*)d_ws;
  float* h      = (float*)(ws);
  float* E1     = (float*)(ws + 8388608);
  float* E2p    = (float*)(ws + 8454144);
  float* denomP = (float*)(ws + 8519680);
  u64*   mask   = (u64*)  (ws + 10616832);
  unsigned short* gTp = (unsigned short*)(ws + 14811136);

  k_h  <<<256, 256, 0, stream>>>(x, W, a1, a2, ab, h, E1, E2p);
  k_dm <<<dim3(8, 32, 8), 256, 0, stream>>>(adj, E1, E2p, denomP, mask);
  k_gt <<<dim3(8, 4, 8), 256, 0, stream>>>(h, denomP, gTp);
  k_main<<<dim3(64, 8), 256, 0, stream>>>(E1, E2p, (const uint32*)mask, gTp, out);
}

// Round 9
// 68.648 us; speedup vs baseline: 1.3304x; 1.1350x over previous
//
#include <hip/hip_runtime.h>
#include <stdint.h>

typedef unsigned int  uint32;
typedef unsigned long long u64;

#define L2E 1.44269504088896340736f

typedef float f32x4 __attribute__((ext_vector_type(4)));
typedef short bf16x8 __attribute__((ext_vector_type(8)));

__device__ __forceinline__ unsigned short f2bf(float f){
  uint32 u = __float_as_uint(f);
  u += 0x7fffu + ((u >> 16) & 1u);
  return (unsigned short)(u >> 16);
}

// k-permutation: k' -> j:  Q = k'>>8, p = (k'>>6)&3, l = k'&63, j = Q*256 + 4*l + p
// inverse:       j  -> k': Q = j>>8,  l = (j&255)>>2, p = j&3,  k' = Q*256 + p*64 + l
// gTp fragment layout: element (b, o, k') at
//   ((b*64 + (k'>>5))*8 + (o>>4))*512 + (((k'>>3)&3)*16 + (o&15))*8 + (k'&7)

// ---------------- K1: h = x @ W^T (bf16 split MFMA) + fused E1/E2p epilogue ----------------
__global__ __launch_bounds__(256) void k_h(const float* __restrict__ x,
                                           const float* __restrict__ W,
                                           const float* __restrict__ a1,
                                           const float* __restrict__ a2,
                                           const float* __restrict__ ab,
                                           float* __restrict__ h,
                                           float* __restrict__ E1,
                                           float* __restrict__ E2p){
  __shared__ unsigned short xs[2][64][72];    // [hi/lo][row][f] pad 72
  __shared__ unsigned short wsm[2][128][72];  // [hi/lo][o][f]
  const int tid = threadIdx.x;
  const int wv = tid >> 6, lane = tid & 63;
  const int r = lane & 15, kg = lane >> 4;
  const int row0 = blockIdx.x * 64;

  f32x4 acc[8];
  #pragma unroll
  for (int of = 0; of < 8; ++of) acc[of] = (f32x4){0.f,0.f,0.f,0.f};

  for (int kc = 0; kc < 4; ++kc){
    if (kc) __syncthreads();
    #pragma unroll
    for (int it = 0; it < 4; ++it){
      int idx = tid + it * 256;
      int row = idx >> 4, f = (idx & 15) * 4;
      float4 v = *(const float4*)(x + (size_t)(row0 + row) * 256 + kc * 64 + f);
      ushort4 hi, lo;
      { unsigned short hh = f2bf(v.x); float rr = v.x - __uint_as_float(((uint32)hh)<<16); hi.x = hh; lo.x = f2bf(rr); }
      { unsigned short hh = f2bf(v.y); float rr = v.y - __uint_as_float(((uint32)hh)<<16); hi.y = hh; lo.y = f2bf(rr); }
      { unsigned short hh = f2bf(v.z); float rr = v.z - __uint_as_float(((uint32)hh)<<16); hi.z = hh; lo.z = f2bf(rr); }
      { unsigned short hh = f2bf(v.w); float rr = v.w - __uint_as_float(((uint32)hh)<<16); hi.w = hh; lo.w = f2bf(rr); }
      *(ushort4*)&xs[0][row][f] = hi;
      *(ushort4*)&xs[1][row][f] = lo;
    }
    #pragma unroll
    for (int it = 0; it < 8; ++it){
      int idx = tid + it * 256;
      int o = idx >> 4, f = (idx & 15) * 4;
      float4 v = *(const float4*)(W + (size_t)o * 256 + kc * 64 + f);
      ushort4 hi, lo;
      { unsigned short hh = f2bf(v.x); float rr = v.x - __uint_as_float(((uint32)hh)<<16); hi.x = hh; lo.x = f2bf(rr); }
      { unsigned short hh = f2bf(v.y); float rr = v.y - __uint_as_float(((uint32)hh)<<16); hi.y = hh; lo.y = f2bf(rr); }
      { unsigned short hh = f2bf(v.z); float rr = v.z - __uint_as_float(((uint32)hh)<<16); hi.z = hh; lo.z = f2bf(rr); }
      { unsigned short hh = f2bf(v.w); float rr = v.w - __uint_as_float(((uint32)hh)<<16); hi.w = hh; lo.w = f2bf(rr); }
      *(ushort4*)&wsm[0][o][f] = hi;
      *(ushort4*)&wsm[1][o][f] = lo;
    }
    __syncthreads();
    #pragma unroll
    for (int kk = 0; kk < 2; ++kk){
      bf16x8 ah = *(const bf16x8*)&xs[0][wv*16 + r][kk*32 + kg*8];
      bf16x8 al = *(const bf16x8*)&xs[1][wv*16 + r][kk*32 + kg*8];
      #pragma unroll
      for (int of = 0; of < 8; ++of){
        bf16x8 bh = *(const bf16x8*)&wsm[0][of*16 + r][kk*32 + kg*8];
        bf16x8 bl = *(const bf16x8*)&wsm[1][of*16 + r][kk*32 + kg*8];
        acc[of] = __builtin_amdgcn_mfma_f32_16x16x32_bf16(ah, bh, acc[of], 0, 0, 0);
        acc[of] = __builtin_amdgcn_mfma_f32_16x16x32_bf16(ah, bl, acc[of], 0, 0, 0);
        acc[of] = __builtin_amdgcn_mfma_f32_16x16x32_bf16(al, bh, acc[of], 0, 0, 0);
      }
    }
  }
  #pragma unroll
  for (int of = 0; of < 8; ++of)
    #pragma unroll
    for (int q = 0; q < 4; ++q)
      h[(size_t)(row0 + wv*16 + kg*4 + q) * 128 + of*16 + r] = acc[of][q];

  float p1[4] = {0,0,0,0}, p2[4] = {0,0,0,0};
  #pragma unroll
  for (int of = 0; of < 8; ++of){
    float w1 = a1[of*16 + r], w2 = a2[of*16 + r];
    #pragma unroll
    for (int q = 0; q < 4; ++q){
      p1[q] = fmaf(acc[of][q], w1, p1[q]);
      p2[q] = fmaf(acc[of][q], w2, p2[q]);
    }
  }
  #pragma unroll
  for (int off = 8; off; off >>= 1)
    #pragma unroll
    for (int q = 0; q < 4; ++q){
      p1[q] += __shfl_xor(p1[q], off);
      p2[q] += __shfl_xor(p2[q], off);
    }
  if (r == 0){
    float abv = ab[0];
    #pragma unroll
    for (int q = 0; q < 4; ++q){
      int row = row0 + wv*16 + kg*4 + q;
      E1[row] = p1[q] * L2E;
      int bb = row >> 11, j = row & 2047;
      int kp = (j & ~255) + (j & 3) * 64 + ((j & 255) >> 2);
      E2p[bb * 2048 + kp] = (p2[q] + abv) * L2E;
    }
  }
}

// ---------------- K2: denom partials + mask in k'-order (R3-proven config) ----------------
// grid (Q=8, ic=8, b=8) = 512 blocks, 4 waves/block; wave covers 256 j x 64 i rows, float4/lane.
__global__ __launch_bounds__(256) void k_dm(const float* __restrict__ adj,
                                            const float* __restrict__ E1,
                                            const float* __restrict__ E2p,
                                            float* __restrict__ denomP,
                                            u64* __restrict__ mask){
  __shared__ float red[4][256];
  const int b = blockIdx.z, Q = blockIdx.x, ic = blockIdx.y;
  const int wv = threadIdx.x >> 6, lane = threadIdx.x & 63;
  const int Jbase = Q * 256;
  const int row0 = ic * 256 + wv * 64;

  const float* e1p = E1 + b * 2048 + row0;
  const f32x4* ap = (const f32x4*)(adj + (size_t)(b * 2048 + row0) * 2048 + Jbase) + lane;
  u64* mp = mask + (size_t)(b * 2048 + row0) * 32 + Q * 4;

  float e2v[4];
  #pragma unroll
  for (int p = 0; p < 4; ++p)
    e2v[p] = E2p[b * 2048 + Q * 256 + p * 64 + lane];

  float ds0 = 0.f, ds1 = 0.f, ds2 = 0.f, ds3 = 0.f;

  for (int r0 = 0; r0 < 64; r0 += 8){
    f32x4 av[8];
    #pragma unroll
    for (int u = 0; u < 8; ++u)
      av[u] = ap[(size_t)(r0 + u) * 512];
    #pragma unroll
    for (int u = 0; u < 8; ++u){
      const float e1 = e1p[r0 + u];
      float t0 = e1 + e2v[0]; t0 = fmaxf(t0, 0.2f * t0);
      float t1 = e1 + e2v[1]; t1 = fmaxf(t1, 0.2f * t1);
      float t2 = e1 + e2v[2]; t2 = fmaxf(t2, 0.2f * t2);
      float t3 = e1 + e2v[3]; t3 = fmaxf(t3, 0.2f * t3);
      ds0 = fmaf(av[u][0], __builtin_amdgcn_exp2f(t0), ds0);
      ds1 = fmaf(av[u][1], __builtin_amdgcn_exp2f(t1), ds1);
      ds2 = fmaf(av[u][2], __builtin_amdgcn_exp2f(t2), ds2);
      ds3 = fmaf(av[u][3], __builtin_amdgcn_exp2f(t3), ds3);
      u64 b0 = __ballot(av[u][0] != 0.f);
      u64 b1 = __ballot(av[u][1] != 0.f);
      u64 b2 = __ballot(av[u][2] != 0.f);
      u64 b3 = __ballot(av[u][3] != 0.f);
      if (lane == 0){
        ulonglong2* dst = (ulonglong2*)(mp + (size_t)(r0 + u) * 32);
        dst[0] = (ulonglong2){b0, b1};
        dst[1] = (ulonglong2){b2, b3};
      }
    }
  }

  *(float4*)&red[wv][lane * 4] = (float4){ds0, ds1, ds2, ds3};
  __syncthreads();
  const int t = threadIdx.x;
  denomP[(size_t)ic * 16384 + b * 2048 + Jbase + t] = red[0][t] + red[1][t] + red[2][t] + red[3][t];
}

// ---------------- K3: gTp[frag-order] = bf16( h[b][j(k')][o] / denom[j(k')] ) ----------------
// grid (Q=8, ot=4, b=8)
__global__ __launch_bounds__(256) void k_gt(const float* __restrict__ h,
                                            const float* __restrict__ denomP,
                                            unsigned short* __restrict__ gTp){
  __shared__ float hl[8464];   // index: j*33 + (j>>4) + oo,  oo<32 (local node order)
  __shared__ float rrec[256];
  const int b = blockIdx.z, Q = blockIdx.x, ot = blockIdx.y;
  const int o0 = ot * 32;
  const int tid = threadIdx.x;

  {
    float d = 0.f;
    #pragma unroll
    for (int icc = 0; icc < 8; ++icc)
      d += denomP[(size_t)icc * 16384 + b * 2048 + Q * 256 + tid];
    rrec[tid] = 1.0f / d;
  }
  __syncthreads();

  #pragma unroll
  for (int it = 0; it < 8; ++it){
    int idx = tid + it * 256;
    int j = idx >> 3, f = idx & 7;
    float4 v = *(const float4*)(h + (size_t)(b * 2048 + Q * 256 + j) * 128 + o0 + f * 4);
    float rc = rrec[j];
    int base = j * 33 + (j >> 4) + f * 4;
    hl[base + 0] = v.x * rc;
    hl[base + 1] = v.y * rc;
    hl[base + 2] = v.z * rc;
    hl[base + 3] = v.w * rc;
  }
  __syncthreads();

  const int u  = tid & 127;
  const int fh = tid >> 7;
  const int lane = u >> 1;
  const int e0 = (u & 1) * 4;
  const int orow_r = lane & 15;
  const int kgrp = lane >> 4;
  #pragma unroll
  for (int it = 0; it < 8; ++it){
    int f  = it * 2 + fh;
    int kb = f >> 1, sl = f & 1;
    int orow = sl * 16 + orow_r;
    int klb = kb * 32 + kgrp * 8 + e0;
    ushort4 uu;
    { int kl = klb + 0; int jl = 4 * (kl & 63) + (kl >> 6); uu.x = f2bf(hl[jl * 33 + (jl >> 4) + orow]); }
    { int kl = klb + 1; int jl = 4 * (kl & 63) + (kl >> 6); uu.y = f2bf(hl[jl * 33 + (jl >> 4) + orow]); }
    { int kl = klb + 2; int jl = 4 * (kl & 63) + (kl >> 6); uu.z = f2bf(hl[jl * 33 + (jl >> 4) + orow]); }
    { int kl = klb + 3; int jl = 4 * (kl & 63) + (kl >> 6); uu.w = f2bf(hl[jl * 33 + (jl >> 4) + orow]); }
    size_t dst = ((size_t)((b * 64 + Q * 8 + kb) * 8 + (ot * 2 + sl))) * 512 + lane * 8 + e0;
    *(ushort4*)(gTp + dst) = uu;
  }
}

// ---------------- K4: out = ELU( A @ g ), A synthesized, B coalesced frag loads ----------------
__global__ __launch_bounds__(256) void k_main(const float* __restrict__ E1,
                                              const float* __restrict__ E2p,
                                              const uint32* __restrict__ mask32,
                                              const unsigned short* __restrict__ gTp,
                                              float* __restrict__ out){
  __shared__ float cmb[4][32][129];
  const int b  = blockIdx.y;
  const int ib = blockIdx.x;
  const int wv = threadIdx.x >> 6, lane = threadIdx.x & 63;
  const int r  = lane & 15, kg = lane >> 4;
  const int gi0 = b * 2048 + ib * 32 + r;
  const float e1_0 = E1[gi0];
  const float e1_1 = E1[gi0 + 16];
  const uint32* m0 = mask32 + (size_t)gi0 * 64;
  const uint32* m1 = mask32 + (size_t)(gi0 + 16) * 64;

  f32x4 acc[2][8];
  #pragma unroll
  for (int si = 0; si < 2; ++si)
    #pragma unroll
    for (int so = 0; so < 8; ++so)
      acc[si][so] = (f32x4){0.f, 0.f, 0.f, 0.f};

  const int k0 = wv * 512, k1 = k0 + 512;
  for (int kk = k0; kk < k1; kk += 32){
    const int j0 = kk + kg * 8;
    const float4 eA = *(const float4*)(E2p + b * 2048 + j0);
    const float4 eB = *(const float4*)(E2p + b * 2048 + j0 + 4);
    const uint32 bits0 = (m0[kk >> 5] >> (kg * 8)) & 0xffu;
    const uint32 bits1 = (m1[kk >> 5] >> (kg * 8)) & 0xffu;
    float e2v[8] = {eA.x, eA.y, eA.z, eA.w, eB.x, eB.y, eB.z, eB.w};

    union { uint32 u[4]; bf16x8 v; } af0, af1;
    #pragma unroll
    for (int p = 0; p < 4; ++p){
      {
        float t0 = e1_0 + e2v[2*p];     t0 = fmaxf(t0, 0.2f * t0);
        float t1 = e1_0 + e2v[2*p+1];   t1 = fmaxf(t1, 0.2f * t1);
        float x0 = ((bits0 >> (2*p))   & 1u) ? __builtin_amdgcn_exp2f(t0) : 0.f;
        float x1 = ((bits0 >> (2*p+1)) & 1u) ? __builtin_amdgcn_exp2f(t1) : 0.f;
        uint32 u0 = __float_as_uint(x0); u0 = (u0 + 0x7fffu + ((u0 >> 16) & 1u)) >> 16;
        uint32 u1 = __float_as_uint(x1); u1 = (u1 + 0x7fffu + ((u1 >> 16) & 1u)) & 0xffff0000u;
        af0.u[p] = u0 | u1;
      }
      {
        float t0 = e1_1 + e2v[2*p];     t0 = fmaxf(t0, 0.2f * t0);
        float t1 = e1_1 + e2v[2*p+1];   t1 = fmaxf(t1, 0.2f * t1);
        float x0 = ((bits1 >> (2*p))   & 1u) ? __builtin_amdgcn_exp2f(t0) : 0.f;
        float x1 = ((bits1 >> (2*p+1)) & 1u) ? __builtin_amdgcn_exp2f(t1) : 0.f;
        uint32 u0 = __float_as_uint(x0); u0 = (u0 + 0x7fffu + ((u0 >> 16) & 1u)) >> 16;
        uint32 u1 = __float_as_uint(x1); u1 = (u1 + 0x7fffu + ((u1 >> 16) & 1u)) & 0xffff0000u;
        af1.u[p] = u0 | u1;
      }
    }
    const unsigned short* gk = gTp + ((size_t)(b * 64 + (kk >> 5)) * 8) * 512 + lane * 8;
    #pragma unroll
    for (int so = 0; so < 8; ++so){
      bf16x8 bfr = *(const bf16x8*)(gk + so * 512);
      acc[0][so] = __builtin_amdgcn_mfma_f32_16x16x32_bf16(af0.v, bfr, acc[0][so], 0, 0, 0);
      acc[1][so] = __builtin_amdgcn_mfma_f32_16x16x32_bf16(af1.v, bfr, acc[1][so], 0, 0, 0);
    }
  }

  #pragma unroll
  for (int si = 0; si < 2; ++si)
    #pragma unroll
    for (int so = 0; so < 8; ++so)
      #pragma unroll
      for (int q = 0; q < 4; ++q){
        int il = si * 16 + kg * 4 + q;
        int o  = so * 16 + r;
        cmb[wv][il][o] = acc[si][so][q];
      }
  __syncthreads();
  for (int e = threadIdx.x; e < 4096; e += 256){
    int i = e >> 7, o = e & 127;
    float v = cmb[0][i][o] + cmb[1][i][o] + cmb[2][i][o] + cmb[3][i][o];
    float res = v > 0.f ? v : (__builtin_amdgcn_exp2f(v * L2E) - 1.0f);
    out[(size_t)(b * 2048 + ib * 32 + i) * 128 + o] = res;
  }
}

// ---------------- launch ----------------
extern "C" void kernel_launch(void* const* d_in, const int* in_sizes, int n_in,
                              void* d_out, int out_size, void* d_ws, size_t ws_size,
                              hipStream_t stream){
  const float* x   = (const float*)d_in[0];
  const float* adj = (const float*)d_in[1];
  const float* W   = (const float*)d_in[2];
  const float* a1  = (const float*)d_in[3];
  const float* a2  = (const float*)d_in[4];
  const float* ab  = (const float*)d_in[5];
  float* out = (float*)d_out;

  // ws layout (bytes):
  //   h      f32 [16384*128]      @ 0          (8,388,608)
  //   E1     f32 [16384]          @ 8388608    (65,536)
  //   E2p    f32 [16384]          @ 8454144    (65,536)
  //   denomP f32 [8][16384]       @ 8519680    (524,288)
  //   mask   u64 [8*2048*32]      @ 9043968    (4,194,304)
  //   gTp    bf16[8*64*8*512]     @ 13238272   (4,194,304)
  const size_t WS_NEEDED = 17432576;
  if (ws_size < WS_NEEDED) return;

  char* ws = (char*)d_ws;
  float* h      = (float*)(ws);
  float* E1     = (float*)(ws + 8388608);
  float* E2p    = (float*)(ws + 8454144);
  float* denomP = (float*)(ws + 8519680);
  u64*   mask   = (u64*)  (ws + 9043968);
  unsigned short* gTp = (unsigned short*)(ws + 13238272);

  k_h  <<<256, 256, 0, stream>>>(x, W, a1, a2, ab, h, E1, E2p);
  k_dm <<<dim3(8, 8, 8), 256, 0, stream>>>(adj, E1, E2p, denomP, mask);
  k_gt <<<dim3(8, 4, 8), 256, 0, stream>>>(h, denomP, gTp);
  k_main<<<dim3(64, 8), 256, 0, stream>>>(E1, E2p, (const uint32*)mask, gTp, out);
}